// Round 9
// baseline (193.099 us; speedup 1.0000x reference)
//
#include <hip/hip_runtime.h>
#include <hip/hip_bf16.h>

typedef __attribute__((ext_vector_type(4))) int   int4x;
typedef __attribute__((ext_vector_type(4))) float floatx4;

#define M_DIM 8192
#define N_DIM 4096
#define K_DIM 4096
#define N_EXC 3277
#define QS    22.0f

typedef unsigned int u32;
typedef __attribute__((address_space(1))) const u32 gu32;
typedef __attribute__((address_space(3))) u32 lu32;

__device__ __forceinline__ void gload_lds16(const void* g, void* l) {
    __builtin_amdgcn_global_load_lds((gu32*)g, (lu32*)l, 16, 0, 0);
}

// ---------------------------------------------------------------------------
// flag: 0 = int32, 1 = bool/u8, 2 = float32
__global__ void detect_kind(const unsigned char* __restrict__ w, int* __restrict__ flag) {
    __shared__ int sF, sO;
    const int tid = threadIdx.x;
    if (tid == 0) { sF = 0; sO = 0; }
    __syncthreads();
    int sawF = 0, sawO = 0;
    const unsigned char* p = w + tid * 16;
    #pragma unroll
    for (int i = 0; i < 16; ++i) {
        unsigned char b = p[i];
        int off = (tid * 16 + i) & 3;
        if (b == 0x3F && off == 3) sawF = 1;
        if (b != 0 && off != 0)    sawO = 1;
    }
    if (sawF) atomicOr(&sF, 1);
    if (sawO) atomicOr(&sO, 1);
    __syncthreads();
    if (tid == 0) *flag = sF ? 2 : (sO ? 1 : 0);
}

// ---------------------------------------------------------------------------
// x (f32) -> xb (i8), q = clamp(round(22*x), -127, 127). EI sign lives in B.
__global__ void conv_x_kernel(const float* __restrict__ x, unsigned char* __restrict__ xb) {
    size_t base = ((size_t)blockIdx.x * 256 + threadIdx.x) * 8;
    floatx4 v0 = *(const floatx4*)(x + base);
    floatx4 v1 = *(const floatx4*)(x + base + 4);
    float f[8];
    f[0] = v0[0]; f[1] = v0[1]; f[2] = v0[2]; f[3] = v0[3];
    f[4] = v1[0]; f[5] = v1[1]; f[6] = v1[2]; f[7] = v1[3];
    u32 lo = 0, hi = 0;
    #pragma unroll
    for (int j = 0; j < 4; ++j) {
        int q = __float2int_rn(f[j] * QS);
        q = q > 127 ? 127 : (q < -127 ? -127 : q);
        lo |= ((u32)(q & 0xff)) << (8 * j);
    }
    #pragma unroll
    for (int j = 0; j < 4; ++j) {
        int q = __float2int_rn(f[4 + j] * QS);
        q = q > 127 ? 127 : (q < -127 ? -127 : q);
        hi |= ((u32)(q & 0xff)) << (8 * j);
    }
    uint2 o; o.x = lo; o.y = hi;
    *(uint2*)(xb + base) = o;
}

// ---------------------------------------------------------------------------
// kernel ([K][N], dtype per flag) -> wbt (i8, [N][K]) transposed;
// value = w ? (k >= N_EXC ? -4 : 1) : 0.
__global__ void conv_w_kernel(const void* __restrict__ w, const int* __restrict__ flag,
                              unsigned char* __restrict__ wbt) {
    __shared__ signed char t[64][65];
    const int kind = *flag;
    const int tid = threadIdx.x;
    const int bx = blockIdx.x & 63;
    const int by = blockIdx.x >> 6;
    const int k0 = by * 64, n0 = bx * 64;
    #pragma unroll
    for (int i = 0; i < 16; ++i) {
        int lin = i * 256 + tid;
        int r = lin >> 6, c = lin & 63;
        size_t gi = (size_t)(k0 + r) * N_DIM + (n0 + c);
        int nz;
        if (kind == 0)      nz = ((const int*)w)[gi] != 0;
        else if (kind == 1) nz = ((const unsigned char*)w)[gi] != 0;
        else                nz = ((const float*)w)[gi] != 0.0f;
        t[r][c] = nz ? ((k0 + r >= N_EXC) ? (signed char)-4 : (signed char)1) : (signed char)0;
    }
    __syncthreads();
    #pragma unroll
    for (int it = 0; it < 4; ++it) {
        int lin = it * 256 + tid;      // 1024 words
        int rr = lin >> 4;             // n within tile
        int cg = lin & 15;             // k-group of 4
        u32 wd = 0;
        #pragma unroll
        for (int j = 0; j < 4; ++j)
            wd |= ((u32)(unsigned char)t[cg * 4 + j][rr]) << (8 * j);
        *(u32*)(wbt + (size_t)(n0 + rr) * K_DIM + k0 + cg * 4) = wd;
    }
}

// ---------------------------------------------------------------------------
// i8 GEMM: C = fs * (A_i8[M][K] x Bt_i8[N][K]^T), fs = scale/22.
// 256x256 tile, BK=64, 8 waves (2x4), 4 LDS bufs, 3-deep gload pipeline,
// INTRA-SIMD WAVE ROLE-SPLIT: wave->SIMD is wid&3, so wr=wid>>2 puts one
// wr0 and one wr1 wave on each SIMD. Per tile:
//   wr0: read(t)  then MFMA(t)
//   wr1: MFMA(t)  (frags read last tile) then read(t+1)
// -> each SIMD's matrix pipe is fed by one wave while the other occupies LDS.
// Safety (no timing races): per-tile vmcnt(4) drains own stage(t+2) (issued
// one tile earlier), so barrier(t) publishes bufs <= t+1 by induction; wr1's
// read-ahead of buf t+1 is behind that barrier. WAR: stage at tile t targets
// buf[(t-1)&3], whose last readers (wr0@t-1, wr1@t-2) passed barrier(t).
// Ledger: outstanding at tile end = [t+3] only, every tile.
__global__ __launch_bounds__(512, 2)
void gemm_i8_kernel(const signed char* __restrict__ A,
                    const signed char* __restrict__ Bt,
                    float* __restrict__ C,
                    const float* __restrict__ scale_p) {
    __shared__ __align__(16) char lds[131072];   // 4 bufs x (A 16K + B 16K)

    const int tid  = threadIdx.x;
    const int wid  = tid >> 6;
    const int lane = tid & 63;
    const int l15  = lane & 15;
    const int l4   = lane >> 4;
    const int wr   = wid >> 2;      // 0..1  (128-row half) == role group
    const int wc   = wid & 3;       // 0..3  (64-col quarter)

    // XCD swizzle: 512 blocks, 8 XCDs, 64 per chunk (bijective)
    int wg = blockIdx.x;
    wg = (wg & 7) * 64 + (wg >> 3);
    const int bm = wg >> 4;
    const int bn = wg & 15;

    const size_t a_base = (size_t)bm * 256 * K_DIM;
    const size_t b_base = (size_t)bn * 256 * K_DIM;

    // staging: 16 units/operand of 16 rows (1 KiB); wave w -> units {2w, 2w+1}
    const int lrow = lane >> 2;                              // 0..15 row in unit
    const int lswz = ((lane & 3) ^ ((lane >> 3) & 3)) << 4;  // pre-swizzled src slot
    const int xs   = ((l15 >> 1) & 3) << 4;                  // read-side slot xor

#define STAGE_A(P, TILE) do { \
    _Pragma("unroll") \
    for (int j_ = 0; j_ < 2; ++j_) { \
        int r0_ = (wid * 2 + j_) * 16; \
        const signed char* g_ = A + a_base + (size_t)(r0_ + lrow) * K_DIM + (TILE)*64 + lswz; \
        gload_lds16(g_, lds + (P)*32768 + r0_*64); \
    } } while (0)

#define STAGE_B(P, TILE) do { \
    _Pragma("unroll") \
    for (int j_ = 0; j_ < 2; ++j_) { \
        int r0_ = (wid * 2 + j_) * 16; \
        const signed char* g_ = Bt + b_base + (size_t)(r0_ + lrow) * K_DIM + (TILE)*64 + lswz; \
        gload_lds16(g_, lds + (P)*32768 + 16384 + r0_*64); \
    } } while (0)

// one A row-block fragment (k = l4*16 + e)
#define RD_A1(P, MI) \
    ar[MI] = *(const int4x*)(lds + (P)*32768 \
        + (wr*128 + (MI)*16 + l15)*64 + (((l4)<<4) ^ xs))

#define RD_B1(P, NI) \
    br[NI] = *(const int4x*)(lds + (P)*32768 + 16384 \
        + (wc*64 + (NI)*16 + l15)*64 + (((l4)<<4) ^ xs))

#define READS(P) do { \
    RD_A1(P,0); RD_B1(P,0); RD_B1(P,1); RD_B1(P,2); RD_B1(P,3); \
    RD_A1(P,1); RD_A1(P,2); RD_A1(P,3); RD_A1(P,4); \
    RD_A1(P,5); RD_A1(P,6); RD_A1(P,7); } while (0)

#define MFMA32() do { \
    __builtin_amdgcn_s_setprio(1); \
    _Pragma("unroll") \
    for (int mi_ = 0; mi_ < 8; ++mi_) { \
        _Pragma("unroll") \
        for (int ni_ = 0; ni_ < 4; ++ni_) \
            acc[mi_][ni_] = __builtin_amdgcn_mfma_i32_16x16x64_i8( \
                ar[mi_], br[ni_], acc[mi_][ni_], 0, 0, 0); \
    } \
    __builtin_amdgcn_s_setprio(0); } while (0)

#define BAR()   __builtin_amdgcn_s_barrier()
#define VM4()   asm volatile("s_waitcnt vmcnt(4)" ::: "memory")

    int4x ar[8], br[4];
    int4x acc[8][4] = {};

    // prologue: tiles 0,1,2 -> bufs 0,1,2 (12 gloads/wave);
    // vmcnt(4) drains stages 0,1; barrier publishes bufs 0,1;
    // wr1 pre-reads tile 0.
    STAGE_A(0, 0); STAGE_B(0, 0);
    STAGE_A(1, 1); STAGE_B(1, 1);
    STAGE_A(2, 2); STAGE_B(2, 2);
    VM4();
    BAR();
    if (wr == 1) { READS(0); }

    for (int t = 0; t < 64; ++t) {
        const int p  = t & 3;
        const int pn = (t + 1) & 3;
        const int p3 = (t + 3) & 3;
        const int t3 = (t + 3) & 63;    // wraps on last iters: WAR-safe, never read
        BAR();                           // publishes bufs <= t+1
        STAGE_A(p3, t3); STAGE_B(p3, t3);
        if (wr == 0) {
            READS(p);                    // tile t
            MFMA32();
        } else {
            MFMA32();                    // tile t (frags from previous iter)
            READS(pn);                   // tile t+1 (published at this BAR)
        }
        VM4();                           // drains own stage(t+2); leaves t+3
    }
    asm volatile("s_waitcnt vmcnt(0) lgkmcnt(0)" ::: "memory");

    // epilogue: i32 -> f32 with fused scale/quant factor
    const float fs = *scale_p * (1.0f / QS);
    const int row0 = bm * 256 + wr * 128;
    const int col0 = bn * 256 + wc * 64;
    #pragma unroll
    for (int mf = 0; mf < 8; ++mf) {
        #pragma unroll
        for (int nf = 0; nf < 4; ++nf) {
            int row = row0 + mf * 16 + l4 * 4;
            int col = col0 + nf * 16 + l15;
            float* cp = C + (size_t)row * N_DIM + col;
            #pragma unroll
            for (int r = 0; r < 4; ++r)
                cp[(size_t)r * N_DIM] = fs * (float)acc[mf][nf][r];
        }
    }
#undef STAGE_A
#undef STAGE_B
#undef RD_A1
#undef RD_B1
#undef READS
#undef MFMA32
#undef BAR
#undef VM4
}

// ---------------------------------------------------------------------------
// Insurance fallback (f32, exact semantics) if workspace is too small.
__global__ void naive_kernel(const float* __restrict__ x, const void* __restrict__ w,
                             const int* __restrict__ flag, const float* __restrict__ scale_p,
                             float* __restrict__ out) {
    int n = blockIdx.x * 256 + threadIdx.x;
    int m = blockIdx.y;
    int kind = *flag;
    const float* xr = x + (size_t)m * K_DIM;
    float acc = 0.f;
    for (int k = 0; k < K_DIM; ++k) {
        float xv = xr[k];
        if (k >= N_EXC) xv = -4.0f * xv;
        size_t gi = (size_t)k * N_DIM + n;
        float wv;
        if (kind == 0)      wv = (float)((const int*)w)[gi];
        else if (kind == 1) wv = (float)((const unsigned char*)w)[gi];
        else                wv = ((const float*)w)[gi];
        acc += xv * wv;
    }
    out[(size_t)m * N_DIM + n] = acc * (*scale_p);
}

extern "C" void kernel_launch(void* const* d_in, const int* in_sizes, int n_in,
                              void* d_out, int out_size, void* d_ws, size_t ws_size,
                              hipStream_t stream) {
    const float* x       = (const float*)d_in[0];
    const void*  w       = d_in[1];
    const float* scale_p = (const float*)d_in[2];
    float* out = (float*)d_out;

    const size_t xb_bytes = (size_t)M_DIM * K_DIM;   // 32 MiB (i8)
    const size_t wb_bytes = (size_t)N_DIM * K_DIM;   // 16 MiB (i8)
    const size_t need = xb_bytes + wb_bytes + 256;

    if (ws_size >= need) {
        unsigned char* xb  = (unsigned char*)d_ws;
        unsigned char* wbt = (unsigned char*)((char*)d_ws + xb_bytes);
        int* flag = (int*)((char*)d_ws + xb_bytes + wb_bytes);
        detect_kind<<<1, 256, 0, stream>>>((const unsigned char*)w, flag);
        conv_x_kernel<<<(M_DIM * K_DIM) / (256 * 8), 256, 0, stream>>>(x, xb);
        conv_w_kernel<<<(K_DIM / 64) * (N_DIM / 64), 256, 0, stream>>>(w, flag, wbt);
        gemm_i8_kernel<<<(M_DIM / 256) * (N_DIM / 256), 512, 0, stream>>>(
            (const signed char*)xb, (const signed char*)wbt, out, scale_p);
    } else if (ws_size >= 4) {
        int* flag = (int*)d_ws;
        detect_kind<<<1, 256, 0, stream>>>((const unsigned char*)w, flag);
        dim3 g(N_DIM / 256, M_DIM);
        naive_kernel<<<g, 256, 0, stream>>>(x, w, flag, scale_p, out);
    }
}

// Round 10
// 184.771 us; speedup vs baseline: 1.0451x; 1.0451x over previous
//
#include <hip/hip_runtime.h>
#include <hip/hip_bf16.h>

typedef __attribute__((ext_vector_type(4))) int   int4x;
typedef __attribute__((ext_vector_type(4))) float floatx4;

#define M_DIM 8192
#define N_DIM 4096
#define K_DIM 4096
#define N_EXC 3277
#define QS    22.0f

typedef unsigned int u32;
typedef __attribute__((address_space(1))) const u32 gu32;
typedef __attribute__((address_space(3))) u32 lu32;

__device__ __forceinline__ void gload_lds16(const void* g, void* l) {
    __builtin_amdgcn_global_load_lds((gu32*)g, (lu32*)l, 16, 0, 0);
}

// ---------------------------------------------------------------------------
// flag: 0 = int32, 1 = bool/u8, 2 = float32
__global__ void detect_kind(const unsigned char* __restrict__ w, int* __restrict__ flag) {
    __shared__ int sF, sO;
    const int tid = threadIdx.x;
    if (tid == 0) { sF = 0; sO = 0; }
    __syncthreads();
    int sawF = 0, sawO = 0;
    const unsigned char* p = w + tid * 16;
    #pragma unroll
    for (int i = 0; i < 16; ++i) {
        unsigned char b = p[i];
        int off = (tid * 16 + i) & 3;
        if (b == 0x3F && off == 3) sawF = 1;
        if (b != 0 && off != 0)    sawO = 1;
    }
    if (sawF) atomicOr(&sF, 1);
    if (sawO) atomicOr(&sO, 1);
    __syncthreads();
    if (tid == 0) *flag = sF ? 2 : (sO ? 1 : 0);
}

// ---------------------------------------------------------------------------
// x (f32) -> xb (i8), q = clamp(round(22*x), -127, 127). EI sign lives in B.
__global__ void conv_x_kernel(const float* __restrict__ x, unsigned char* __restrict__ xb) {
    size_t base = ((size_t)blockIdx.x * 256 + threadIdx.x) * 8;
    floatx4 v0 = *(const floatx4*)(x + base);
    floatx4 v1 = *(const floatx4*)(x + base + 4);
    float f[8];
    f[0] = v0[0]; f[1] = v0[1]; f[2] = v0[2]; f[3] = v0[3];
    f[4] = v1[0]; f[5] = v1[1]; f[6] = v1[2]; f[7] = v1[3];
    u32 lo = 0, hi = 0;
    #pragma unroll
    for (int j = 0; j < 4; ++j) {
        int q = __float2int_rn(f[j] * QS);
        q = q > 127 ? 127 : (q < -127 ? -127 : q);
        lo |= ((u32)(q & 0xff)) << (8 * j);
    }
    #pragma unroll
    for (int j = 0; j < 4; ++j) {
        int q = __float2int_rn(f[4 + j] * QS);
        q = q > 127 ? 127 : (q < -127 ? -127 : q);
        hi |= ((u32)(q & 0xff)) << (8 * j);
    }
    uint2 o; o.x = lo; o.y = hi;
    *(uint2*)(xb + base) = o;
}

// ---------------------------------------------------------------------------
// kernel ([K][N], dtype per flag) -> wbt (i8, [N][K]) transposed;
// value = w ? (k >= N_EXC ? -4 : 1) : 0.
__global__ void conv_w_kernel(const void* __restrict__ w, const int* __restrict__ flag,
                              unsigned char* __restrict__ wbt) {
    __shared__ signed char t[64][65];
    const int kind = *flag;
    const int tid = threadIdx.x;
    const int bx = blockIdx.x & 63;
    const int by = blockIdx.x >> 6;
    const int k0 = by * 64, n0 = bx * 64;
    #pragma unroll
    for (int i = 0; i < 16; ++i) {
        int lin = i * 256 + tid;
        int r = lin >> 6, c = lin & 63;
        size_t gi = (size_t)(k0 + r) * N_DIM + (n0 + c);
        int nz;
        if (kind == 0)      nz = ((const int*)w)[gi] != 0;
        else if (kind == 1) nz = ((const unsigned char*)w)[gi] != 0;
        else                nz = ((const float*)w)[gi] != 0.0f;
        t[r][c] = nz ? ((k0 + r >= N_EXC) ? (signed char)-4 : (signed char)1) : (signed char)0;
    }
    __syncthreads();
    #pragma unroll
    for (int it = 0; it < 4; ++it) {
        int lin = it * 256 + tid;      // 1024 words
        int rr = lin >> 4;             // n within tile
        int cg = lin & 15;             // k-group of 4
        u32 wd = 0;
        #pragma unroll
        for (int j = 0; j < 4; ++j)
            wd |= ((u32)(unsigned char)t[cg * 4 + j][rr]) << (8 * j);
        *(u32*)(wbt + (size_t)(n0 + rr) * K_DIM + k0 + cg * 4) = wd;
    }
}

// ---------------------------------------------------------------------------
// i8 GEMM: C = fs * (A_i8[M][K] x Bt_i8[N][K]^T), fs = scale/22.
// 256x256 tile, BK=128, 8 waves (2x4), m201-template 4-phase schedule:
//   ph1: read A0(8)+B0(4) | stage B0(T+1->p') | lgkmcnt(8) | BAR LGKM0 MFMA(0,0) BAR
//   ph2: read B1(4)       | stage A0(T+2->p)  |            | BAR LGKM0 MFMA(0,1) BAR
//   ph3: read A1(8)       | stage B1(T+2->p)  |            | BAR LGKM0 MFMA(1,1) BAR
//   ph4: (no reads)       | stage A1(T+2->p)  | vmcnt(6)   | BAR       MFMA(1,0) BAR
// br0 held live ph1->ph4 (no re-read; 24 ds_reads/wave/tile).
// vmcnt(6) once per tile: in-order VMEM retirement => all but newest 3
// regions landed => ENTIRE tile T+1 guaranteed, block-wide at ph4's BAR.
// WAR: every staged region's last reader drained at an LGKM0 >= 1 barrier
// earlier (A0 rd ph1/st ph2; B1 rd ph2/st ph3; A1 rd ph3/st ph4;
// B0 rd ph1,ph4/st next ph1).
__global__ __launch_bounds__(512, 2)
void gemm_i8_kernel(const signed char* __restrict__ A,
                    const signed char* __restrict__ Bt,
                    float* __restrict__ C,
                    const float* __restrict__ scale_p) {
    __shared__ __align__(16) char lds[131072];   // 2 bufs x (A 32K + B 32K)

    const int tid  = threadIdx.x;
    const int wid  = tid >> 6;
    const int lane = tid & 63;
    const int l15  = lane & 15;
    const int l4   = lane >> 4;
    const int wr   = wid >> 2;      // 0..1  (128-row half)
    const int wc   = wid & 3;       // 0..3  (64-col quarter)

    // XCD swizzle: 512 blocks, 8 XCDs, 64 per chunk (bijective)
    int wg = blockIdx.x;
    wg = (wg & 7) * 64 + (wg >> 3);
    const int bm = wg >> 4;
    const int bn = wg & 15;

    const size_t a_base = (size_t)bm * 256 * K_DIM;
    const size_t b_base = (size_t)bn * 256 * K_DIM;

    const int u0   = wid * 2;
    const int lrow = lane >> 3;                        // 0..7
    const int lswz = ((lane & 7) ^ lrow) << 4;         // pre-swizzled src byte
    const int xm   = (l15 & 7) << 4;                   // read-side xor

// A region HALF: rows {HALF*64 + (u&8)*16 + (u&7)*8}  == both wr bands' AH=HALF
#define STAGEA(BUF, TILE, HALF) do { \
    _Pragma("unroll") \
    for (int j_ = 0; j_ < 2; ++j_) { \
        int u_ = u0 + j_; \
        int r0_ = (HALF)*64 + ((u_ & 8) << 4) + ((u_ & 7) << 3); \
        const signed char* g_ = A + a_base + (size_t)(r0_ + lrow) * K_DIM + (TILE)*128 + lswz; \
        gload_lds16(g_, lds + (BUF)*65536 + r0_*128); \
    } } while (0)

// B region HALF: rows {HALF*32 + (u>>2)*64 + (u&3)*8} == all 4 wc bands' BH=HALF
#define STAGEB(BUF, TILE, HALF) do { \
    _Pragma("unroll") \
    for (int j_ = 0; j_ < 2; ++j_) { \
        int u_ = u0 + j_; \
        int r0_ = (HALF)*32 + ((u_ >> 2) << 6) + ((u_ & 3) << 3); \
        const signed char* g_ = Bt + b_base + (size_t)(r0_ + lrow) * K_DIM + (TILE)*128 + lswz; \
        gload_lds16(g_, lds + (BUF)*65536 + 32768 + r0_*128); \
    } } while (0)

// A-half fragment reads (8 x ds_read_b128): k = ks*64 + l4*16 + e
#define LDA_(BUF, AH) do { \
    _Pragma("unroll") \
    for (int mi_ = 0; mi_ < 4; ++mi_) { \
        _Pragma("unroll") \
        for (int ks_ = 0; ks_ < 2; ++ks_) \
            ar[mi_][ks_] = *(const int4x*)(lds + (BUF)*65536 \
                + (wr*128 + (AH)*64 + mi_*16 + l15)*128 + (((ks_<<6)|(l4<<4)) ^ xm)); \
    } } while (0)

// B-half fragment reads (4 x ds_read_b128) into bank
#define LDB_(BUF, BH, BANK) do { \
    _Pragma("unroll") \
    for (int ni_ = 0; ni_ < 2; ++ni_) { \
        _Pragma("unroll") \
        for (int ks_ = 0; ks_ < 2; ++ks_) \
            BANK[ni_][ks_] = *(const int4x*)(lds + (BUF)*65536 + 32768 \
                + (wc*64 + (BH)*32 + ni_*16 + l15)*128 + (((ks_<<6)|(l4<<4)) ^ xm)); \
    } } while (0)

// 16 MFMAs: quadrant (AH, BH)
#define MFMA16(AH, BH, BANK) do { \
    __builtin_amdgcn_s_setprio(1); \
    _Pragma("unroll") \
    for (int ks_ = 0; ks_ < 2; ++ks_) { \
        _Pragma("unroll") \
        for (int mi_ = 0; mi_ < 4; ++mi_) { \
            _Pragma("unroll") \
            for (int ni_ = 0; ni_ < 2; ++ni_) \
                acc[(AH)*4+mi_][(BH)*2+ni_] = __builtin_amdgcn_mfma_i32_16x16x64_i8( \
                    ar[mi_][ks_], BANK[ni_][ks_], acc[(AH)*4+mi_][(BH)*2+ni_], 0, 0, 0); \
    } } \
    __builtin_amdgcn_s_setprio(0); } while (0)

#define BAR()   __builtin_amdgcn_s_barrier()
#define LGKM0() do { asm volatile("s_waitcnt lgkmcnt(0)" ::: "memory"); \
                     __builtin_amdgcn_sched_barrier(0); } while (0)
#define LGKM8() asm volatile("s_waitcnt lgkmcnt(8)" ::: "memory")
#define VM6()   asm volatile("s_waitcnt vmcnt(6)" ::: "memory")

    int4x ar[4][2], br0[2][2], br1[2][2];
    int4x acc[8][4] = {};

    // prologue: T0 {A0,B0,B1,A1} -> buf0 (8 loads); T1 {A0,B1,A1} -> buf1 (6).
    // vmcnt(6): in-order retirement leaves exactly T1's 3 regions -> T0 landed.
    STAGEA(0, 0, 0); STAGEB(0, 0, 0); STAGEB(0, 0, 1); STAGEA(0, 0, 1);
    STAGEA(1, 1, 0); STAGEB(1, 1, 1); STAGEA(1, 1, 1);
    VM6();
    BAR();

    for (int ii = 0; ii < 16; ++ii) {
        const int t1 = (2*ii + 1) & 31;
        const int t2 = (2*ii + 2) & 31;
        const int t3 = (2*ii + 3) & 31;

        // ---- tile 2ii (buf0) ----
        // ph1
        LDA_(0, 0); LDB_(0, 0, br0);
        STAGEB(1, t1, 0);                 // B0(T+1 -> buf1)
        LGKM8();
        BAR(); LGKM0(); MFMA16(0, 0, br0); BAR();
        // ph2
        LDB_(0, 1, br1);
        STAGEA(0, t2, 0);                 // A0(T+2 -> buf0)
        BAR(); LGKM0(); MFMA16(0, 1, br1); BAR();
        // ph3
        LDA_(0, 1);
        STAGEB(0, t2, 1);                 // B1(T+2 -> buf0)
        BAR(); LGKM0(); MFMA16(1, 1, br1); BAR();
        // ph4 (no ds_reads; br0 still live from ph1)
        STAGEA(0, t2, 1);                 // A1(T+2 -> buf0)
        VM6();                            // ALL of tile T+1 landed
        BAR(); MFMA16(1, 0, br0); BAR();

        // ---- tile 2ii+1 (buf1) ----
        // ph1
        LDA_(1, 0); LDB_(1, 0, br0);
        STAGEB(0, t2, 0);                 // B0(T+2 -> buf0)
        LGKM8();
        BAR(); LGKM0(); MFMA16(0, 0, br0); BAR();
        // ph2
        LDB_(1, 1, br1);
        STAGEA(1, t3, 0);                 // A0(T+3 -> buf1)
        BAR(); LGKM0(); MFMA16(0, 1, br1); BAR();
        // ph3
        LDA_(1, 1);
        STAGEB(1, t3, 1);                 // B1(T+3 -> buf1)
        BAR(); LGKM0(); MFMA16(1, 1, br1); BAR();
        // ph4
        STAGEA(1, t3, 1);                 // A1(T+3 -> buf1)
        VM6();
        BAR(); MFMA16(1, 0, br0); BAR();
    }
    asm volatile("s_waitcnt vmcnt(0) lgkmcnt(0)" ::: "memory");

    // epilogue: i32 -> f32 with fused scale/quant factor
    const float fs = *scale_p * (1.0f / QS);
    const int row0 = bm * 256 + wr * 128;
    const int col0 = bn * 256 + wc * 64;
    #pragma unroll
    for (int mf = 0; mf < 8; ++mf) {
        #pragma unroll
        for (int nf = 0; nf < 4; ++nf) {
            int row = row0 + mf * 16 + l4 * 4;
            int col = col0 + nf * 16 + l15;
            float* cp = C + (size_t)row * N_DIM + col;
            #pragma unroll
            for (int r = 0; r < 4; ++r)
                cp[(size_t)r * N_DIM] = fs * (float)acc[mf][nf][r];
        }
    }
#undef STAGEA
#undef STAGEB
#undef LDA_
#undef LDB_
#undef MFMA16
#undef BAR
#undef LGKM0
#undef LGKM8
#undef VM6
}

// ---------------------------------------------------------------------------
// Insurance fallback (f32, exact semantics) if workspace is too small.
__global__ void naive_kernel(const float* __restrict__ x, const void* __restrict__ w,
                             const int* __restrict__ flag, const float* __restrict__ scale_p,
                             float* __restrict__ out) {
    int n = blockIdx.x * 256 + threadIdx.x;
    int m = blockIdx.y;
    int kind = *flag;
    const float* xr = x + (size_t)m * K_DIM;
    float acc = 0.f;
    for (int k = 0; k < K_DIM; ++k) {
        float xv = xr[k];
        if (k >= N_EXC) xv = -4.0f * xv;
        size_t gi = (size_t)k * N_DIM + n;
        float wv;
        if (kind == 0)      wv = (float)((const int*)w)[gi];
        else if (kind == 1) wv = (float)((const unsigned char*)w)[gi];
        else                wv = ((const float*)w)[gi];
        acc += xv * wv;
    }
    out[(size_t)m * N_DIM + n] = acc * (*scale_p);
}

extern "C" void kernel_launch(void* const* d_in, const int* in_sizes, int n_in,
                              void* d_out, int out_size, void* d_ws, size_t ws_size,
                              hipStream_t stream) {
    const float* x       = (const float*)d_in[0];
    const void*  w       = d_in[1];
    const float* scale_p = (const float*)d_in[2];
    float* out = (float*)d_out;

    const size_t xb_bytes = (size_t)M_DIM * K_DIM;   // 32 MiB (i8)
    const size_t wb_bytes = (size_t)N_DIM * K_DIM;   // 16 MiB (i8)
    const size_t need = xb_bytes + wb_bytes + 256;

    if (ws_size >= need) {
        unsigned char* xb  = (unsigned char*)d_ws;
        unsigned char* wbt = (unsigned char*)((char*)d_ws + xb_bytes);
        int* flag = (int*)((char*)d_ws + xb_bytes + wb_bytes);
        detect_kind<<<1, 256, 0, stream>>>((const unsigned char*)w, flag);
        conv_x_kernel<<<(M_DIM * K_DIM) / (256 * 8), 256, 0, stream>>>(x, xb);
        conv_w_kernel<<<(K_DIM / 64) * (N_DIM / 64), 256, 0, stream>>>(w, flag, wbt);
        gemm_i8_kernel<<<(M_DIM / 256) * (N_DIM / 256), 512, 0, stream>>>(
            (const signed char*)xb, (const signed char*)wbt, out, scale_p);
    } else if (ws_size >= 4) {
        int* flag = (int*)d_ws;
        detect_kind<<<1, 256, 0, stream>>>((const unsigned char*)w, flag);
        dim3 g(N_DIM / 256, M_DIM);
        naive_kernel<<<g, 256, 0, stream>>>(x, w, flag, scale_p, out);
    }
}